// Round 14
// baseline (194.228 us; speedup 1.0000x reference)
//
#include <hip/hip_runtime.h>

#define NN 50000
#define NE 800000
#define DIM 128
#define NB 1024
#define CTXL 50
#define BN_EPS 1e-5f
#define STRIPS 3125     // NN/16
#define GEMM_BLOCKS 512 // 2 blocks/CU at 64KB LDS
#define NBK 49          // buckets of 1024 rows
#define BCAP 20000      // bucket capacity
#define ABLK 1024       // edges per passA block
#define NAB 782         // ceil(NE/ABLK)

// ---------------- ws layout (float offsets) ----------------
static const size_t OFF_Z    = 0;          // zb bf16 [NN][128]; head aliases here after resid2
static const size_t OFF_AH   = 6400000;    // Ah bf16 [NN][128]; acnt/aofs/btot alias during CSR build
static const size_t OFF_HBF  = 9600000;    // hbf bf16 [NN][128] (fg -> h1)
static const size_t OFF_EDG  = 12800000;   // (col,norm) pairs [NE][2]
static const size_t OFF_RS   = 14400000;   // row_start [NN+1] int
static const size_t OFF_P2   = 14450048;   // BN partials [32][256] f (old cursor region)
static const size_t OFF_SCSH = 14550400;   // scale/shift [256] f
static const size_t OFF_WH   = 14550656;   // Wh bf16 [2][128][128]
static const size_t OFF_WL   = 14567040;   // Wl bf16 [2][128][128]
// aliases in dead regions:
static const size_t OFF_BKT  = OFF_Z + 3200000;  // bkt u64 [49][20000] (CSR build only)
static const size_t OFF_ACNT = OFF_AH;           // cnt int [49][784]
static const size_t OFF_AOFS = OFF_AH + 40000;   // ofs int [49][784]
static const size_t OFF_BTOT = OFF_AH + 80000;   // btot int [49]
static const size_t OFF_QIN  = OFF_Z;            // qin bf16 [1024][256] (head phase)
static const size_t OFF_CAT  = OFF_Z + 131072;
static const size_t OFF_FWB  = OFF_Z + 393216;
static const size_t OFF_P1B  = OFF_Z + 409600;
static const size_t OFF_P2B  = OFF_Z + 442368;   // end 458752

typedef __attribute__((ext_vector_type(8))) short s16x8;
typedef __attribute__((ext_vector_type(4))) float fx4;

__device__ __forceinline__ unsigned short f2bf(float f) {
    unsigned u = __float_as_uint(f);
    unsigned r = u + 0x7FFFu + ((u >> 16) & 1u);
    return (unsigned short)(r >> 16);
}
__device__ __forceinline__ float bf2f(unsigned short b) {
    return __uint_as_float((unsigned)b << 16);
}

// ---------------- CSR pass A count + W split + h cast + P2 zero (fused) ----------------
__global__ __launch_bounds__(256) void csr_prep_kernel(const int* __restrict__ row,
                                                       const float* __restrict__ W,
                                                       const float* __restrict__ fg,
                                                       int* __restrict__ cnt,
                                                       unsigned short* __restrict__ Wh,
                                                       unsigned short* __restrict__ Wl,
                                                       unsigned short* __restrict__ hbf,
                                                       float* __restrict__ P2) {
    int i = blockIdx.x * 256 + threadIdx.x;
    if (i < 2 * DIM * DIM) {
        float v = W[i];
        unsigned short h = f2bf(v);
        Wh[i] = h;
        Wl[i] = f2bf(v - bf2f(h));
    }
    if (i < NN * DIM / 4) {
        float4 v = reinterpret_cast<const float4*>(fg)[i];
        reinterpret_cast<ushort4*>(hbf)[i] =
            make_ushort4(f2bf(v.x), f2bf(v.y), f2bf(v.z), f2bf(v.w));
    }
    if (blockIdx.x >= 6218) {  // last 32 blocks zero P2[32][256]
        P2[(blockIdx.x - 6218) * 256 + threadIdx.x] = 0.f;
    }
    if (blockIdx.x < NAB) {
        __shared__ int c[NBK];
        int t = threadIdx.x;
        if (t < NBK) c[t] = 0;
        __syncthreads();
        int base = blockIdx.x * ABLK;
        #pragma unroll
        for (int k = 0; k < 4; k++) {
            int e = base + k * 256 + t;
            if (e < NE) atomicAdd(&c[row[e] >> 10], 1);
        }
        __syncthreads();
        if (t < NBK) cnt[t * 784 + blockIdx.x] = c[t];
    }
}

__global__ __launch_bounds__(1024) void binA_scan(const int* __restrict__ cnt,
                                                  int* __restrict__ ofs,
                                                  int* __restrict__ btot) {
    __shared__ int lds[1024];
    int b = blockIdx.x, t = threadIdx.x;
    int v = (t < NAB) ? cnt[b * 784 + t] : 0;
    lds[t] = v;
    __syncthreads();
    for (int off = 1; off < 1024; off <<= 1) {
        int add = (t >= off) ? lds[t - off] : 0;
        __syncthreads();
        lds[t] += add;
        __syncthreads();
    }
    if (t < NAB) ofs[b * 784 + t] = lds[t] - v;
    if (t == NAB - 1) btot[b] = lds[t];
}

__global__ __launch_bounds__(256) void binA_scatter(const int* __restrict__ row,
                                                    const int* __restrict__ col,
                                                    const float* __restrict__ norm,
                                                    const int* __restrict__ ofs,
                                                    unsigned long long* __restrict__ bkt) {
    __shared__ int c[NBK], bofs[NBK], brsv[NBK];
    __shared__ unsigned long long stage[ABLK];
    __shared__ unsigned char stgb[ABLK];
    int t = threadIdx.x;
    if (t < NBK) c[t] = 0;
    __syncthreads();
    int base = blockIdx.x * ABLK;
    int my_b[4], my_i[4];
    unsigned long long my_pk[4];
    #pragma unroll
    for (int k = 0; k < 4; k++) {
        int e = base + k * 256 + t;
        if (e < NE) {
            int r = row[e];
            int b = r >> 10;
            my_b[k] = b;
            my_i[k] = atomicAdd(&c[b], 1);
            my_pk[k] = ((unsigned long long)__float_as_uint(norm[e]) << 32)
                     | ((unsigned long long)(unsigned)col[e] << 10)
                     | (unsigned)(r & 1023);
        } else my_b[k] = -1;
    }
    __syncthreads();
    if (t == 0) {
        int s = 0;
        for (int b = 0; b < NBK; b++) { bofs[b] = s; s += c[b]; }
    }
    if (t < NBK) brsv[t] = ofs[t * 784 + blockIdx.x];
    __syncthreads();
    #pragma unroll
    for (int k = 0; k < 4; k++) {
        if (my_b[k] >= 0) {
            int j = bofs[my_b[k]] + my_i[k];
            stage[j] = my_pk[k];
            stgb[j] = (unsigned char)my_b[k];
        }
    }
    __syncthreads();
    int tot = min(NE - base, ABLK);
    for (int j = t; j < tot; j += 256) {
        int b = stgb[j];
        int dst = brsv[b] + (j - bofs[b]);
        if (dst < BCAP) bkt[(size_t)b * BCAP + dst] = stage[j];
    }
}

// pass B fused: histogram + prefix -> row_start, then scatter
__global__ __launch_bounds__(1024) void binB_kernel(const unsigned long long* __restrict__ bkt,
                                                    const int* __restrict__ btot,
                                                    int* __restrict__ row_start,
                                                    unsigned long long* __restrict__ edge_out) {
    __shared__ int c[1024];
    __shared__ int rs[1024];
    __shared__ int gofs_s;
    int b = blockIdx.x, t = threadIdx.x;
    c[t] = 0;
    if (t < 64) {
        int v = (t < b) ? btot[t] : 0;
        #pragma unroll
        for (int off = 32; off; off >>= 1) v += __shfl_down(v, off);
        if (t == 0) gofs_s = v;
    }
    __syncthreads();
    int n = btot[b];
    size_t bb = (size_t)b * BCAP;
    for (int i = t; i < n; i += 1024)
        atomicAdd(&c[(int)(bkt[bb + i] & 1023u)], 1);
    __syncthreads();
    int myc = c[t];
    for (int off = 1; off < 1024; off <<= 1) {
        int add = (t >= off) ? c[t - off] : 0;
        __syncthreads();
        c[t] += add;
        __syncthreads();
    }
    int excl = gofs_s + c[t] - myc;
    rs[t] = excl;
    int r = (b << 10) + t;
    if (r <= NN) row_start[r] = excl;
    __syncthreads();
    c[t] = 0;
    __syncthreads();
    for (int i = t; i < n; i += 1024) {
        unsigned long long pk = bkt[bb + i];
        int lr = (int)(pk & 1023u);
        unsigned colv = (unsigned)((pk >> 10) & 0xFFFFu);
        unsigned nrm = (unsigned)(pk >> 32);
        int k = atomicAdd(&c[lr], 1);
        edge_out[rs[lr] + k] = ((unsigned long long)nrm << 32) | colv;
    }
}

// ---------------- aggregation: one wave per row, half-wave split, 8-deep unroll ----------------
__global__ __launch_bounds__(256) void agg_bf_kernel(const unsigned short* __restrict__ hbf,
                                                     const int* __restrict__ row_start,
                                                     const float* __restrict__ edge_s,
                                                     unsigned short* __restrict__ Ah) {
    int gw = (blockIdx.x * 256 + threadIdx.x) >> 6;
    int lane = threadIdx.x & 63;
    int half = lane >> 5;
    int c4 = (lane & 31) * 4;
    if (gw >= NN) return;
    int s = row_start[gw];
    int e = row_start[gw + 1];
    const int2* ep = (const int2*)edge_s;
    float a0 = 0.f, a1 = 0.f, a2 = 0.f, a3 = 0.f;
    int j = s + half;
    for (; j + 14 < e; j += 16) {  // 8 edges per half per iter (stride 2)
        int2 p[8];
        ushort4 v[8];
        #pragma unroll
        for (int k = 0; k < 8; k++) p[k] = ep[j + 2 * k];
        #pragma unroll
        for (int k = 0; k < 8; k++) v[k] = *(const ushort4*)(hbf + (size_t)p[k].x * DIM + c4);
        #pragma unroll
        for (int k = 0; k < 8; k++) {
            float w = __int_as_float(p[k].y);
            a0 = fmaf(w, bf2f(v[k].x), a0); a1 = fmaf(w, bf2f(v[k].y), a1);
            a2 = fmaf(w, bf2f(v[k].z), a2); a3 = fmaf(w, bf2f(v[k].w), a3);
        }
    }
    for (; j < e; j += 2) {
        int2 p = ep[j];
        ushort4 v = *(const ushort4*)(hbf + (size_t)p.x * DIM + c4);
        float w = __int_as_float(p.y);
        a0 = fmaf(w, bf2f(v.x), a0); a1 = fmaf(w, bf2f(v.y), a1);
        a2 = fmaf(w, bf2f(v.z), a2); a3 = fmaf(w, bf2f(v.w), a3);
    }
    a0 += __shfl_xor(a0, 32); a1 += __shfl_xor(a1, 32);
    a2 += __shfl_xor(a2, 32); a3 += __shfl_xor(a3, 32);
    if (half == 0) {
        *(ushort4*)(Ah + (size_t)gw * DIM + c4) =
            make_ushort4(f2bf(a0), f2bf(a1), f2bf(a2), f2bf(a3));
    }
}

// ---------------- z = relu(agg @ W^T): full W in 64KB LDS; BN partials -> P2[32][256] atomic ----
__global__ __launch_bounds__(256) void gemm_mfma_kernel(const unsigned short* __restrict__ Ah,
                                                        const unsigned short* __restrict__ Wh,
                                                        const unsigned short* __restrict__ Wl,
                                                        unsigned short* __restrict__ zb,
                                                        float* __restrict__ P2) {
    __shared__ __align__(16) short Wlds[2][128][128];  // 64 KB
    int tid = threadIdx.x;
    int lane = tid & 63;
    int w = tid >> 6;
    int r16 = lane & 15;
    int kg = lane >> 4;

    #pragma unroll
    for (int ff = 0; ff < 16; ff++) {
        int f = ff * 256 + tid;
        int plane = f >> 11;
        int c = (f >> 4) & 127;
        int ck = f & 15;
        const unsigned short* srcp = (plane ? Wl : Wh) + (size_t)c * DIM + ck * 8;
        *(s16x8*)&Wlds[plane][c][(ck ^ (c & 7)) * 8] = *(const s16x8*)srcp;
    }
    __syncthreads();

    float bsum[2][4] = {{0.f}}, bsq[2][4] = {{0.f}};

    for (int strip = blockIdx.x; strip < STRIPS; strip += GEMM_BLOCKS) {
        size_t abase = (size_t)(strip * 16 + r16) * DIM + kg * 8;
        s16x8 b[4];
        #pragma unroll
        for (int ks = 0; ks < 4; ks++) b[ks] = *(const s16x8*)(Ah + abase + ks * 32);

        fx4 acc[2];
        acc[0] = (fx4){0.f, 0.f, 0.f, 0.f};
        acc[1] = (fx4){0.f, 0.f, 0.f, 0.f};
        #pragma unroll
        for (int ks = 0; ks < 4; ks++) {
            #pragma unroll
            for (int ct = 0; ct < 2; ct++) {
                int wrow = w * 32 + ct * 16 + r16;
                int wch = ((ks * 4 + kg) ^ (r16 & 7)) * 8;
                s16x8 wh8 = *(const s16x8*)&Wlds[0][wrow][wch];
                s16x8 wl8 = *(const s16x8*)&Wlds[1][wrow][wch];
                acc[ct] = __builtin_amdgcn_mfma_f32_16x16x32_bf16(wh8, b[ks], acc[ct], 0, 0, 0);
                acc[ct] = __builtin_amdgcn_mfma_f32_16x16x32_bf16(wl8, b[ks], acc[ct], 0, 0, 0);
            }
        }
        size_t zrow = (size_t)(strip * 16 + r16) * DIM + w * 32 + kg * 4;
        #pragma unroll
        for (int ct = 0; ct < 2; ct++) {
            float x0 = fmaxf(acc[ct][0], 0.f);
            float x1 = fmaxf(acc[ct][1], 0.f);
            float x2 = fmaxf(acc[ct][2], 0.f);
            float x3 = fmaxf(acc[ct][3], 0.f);
            bsum[ct][0] += x0; bsq[ct][0] += x0 * x0;
            bsum[ct][1] += x1; bsq[ct][1] += x1 * x1;
            bsum[ct][2] += x2; bsq[ct][2] += x2 * x2;
            bsum[ct][3] += x3; bsq[ct][3] += x3 * x3;
            *(ushort4*)(zb + zrow + ct * 16) = make_ushort4(f2bf(x0), f2bf(x1), f2bf(x2), f2bf(x3));
        }
    }

    int prow = (blockIdx.x & 31) * 256;
    #pragma unroll
    for (int ct = 0; ct < 2; ct++) {
        #pragma unroll
        for (int jj = 0; jj < 4; jj++) {
            float s = bsum[ct][jj], q = bsq[ct][jj];
            #pragma unroll
            for (int off = 1; off <= 8; off <<= 1) {
                s += __shfl_xor(s, off);
                q += __shfl_xor(q, off);
            }
            if (r16 == 0) {
                int ch = w * 32 + ct * 16 + kg * 4 + jj;
                unsafeAtomicAdd(&P2[prow + ch], s);
                unsafeAtomicAdd(&P2[prow + 128 + ch], q);
            }
        }
    }
}

// ---------------- BN finalize: 32-row reduce, self-zero P2 ----------------
__global__ __launch_bounds__(256) void bn_finalize_kernel(float* __restrict__ P2,
                                                          const float* __restrict__ gamma,
                                                          const float* __restrict__ beta,
                                                          float* __restrict__ scsh) {
    __shared__ float tot[256];
    int t = threadIdx.x;
    float s = 0.f;
    #pragma unroll
    for (int r = 0; r < 32; r++) s += P2[r * 256 + t];
    tot[t] = s;
    __syncthreads();
    if (t < 128) {
        float sum = tot[t];
        float sq  = tot[128 + t];
        float mu = sum * (1.f / (float)NN);
        float var = sq * (1.f / (float)NN) - mu * mu;
        float sc = gamma[t] / sqrtf(var + BN_EPS);
        scsh[t] = sc;
        scsh[128 + t] = beta[t] - mu * sc;
    }
    #pragma unroll
    for (int r = 0; r < 32; r++) P2[r * 256 + t] = 0.f;  // ready for next layer
}

// ---------------- residual: h_new = h_bf + zb*scale + shift; write hbf (layer1) or G fp32 (layer2) ----
__global__ __launch_bounds__(256) void residual_kernel(unsigned short* __restrict__ hbf,
                                                       const unsigned short* __restrict__ zb,
                                                       const float* __restrict__ scsh,
                                                       float* __restrict__ Gout) {
    int i = blockIdx.x * 256 + threadIdx.x;  // ushort4 index
    if (i >= NN * DIM / 4) return;
    int c = (i * 4) & 127;
    ushort4 z4 = reinterpret_cast<const ushort4*>(zb)[i];
    ushort4 h4 = reinterpret_cast<const ushort4*>(hbf)[i];
    float4 sc = *reinterpret_cast<const float4*>(scsh + c);
    float4 sh = *reinterpret_cast<const float4*>(scsh + 128 + c);
    float4 o;
    o.x = bf2f(h4.x) + bf2f(z4.x) * sc.x + sh.x;
    o.y = bf2f(h4.y) + bf2f(z4.y) * sc.y + sh.y;
    o.z = bf2f(h4.z) + bf2f(z4.z) * sc.z + sh.z;
    o.w = bf2f(h4.w) + bf2f(z4.w) * sc.w + sh.w;
    if (Gout) {
        reinterpret_cast<float4*>(Gout)[i] = o;
    } else {
        reinterpret_cast<ushort4*>(hbf)[i] =
            make_ushort4(f2bf(o.x), f2bf(o.y), f2bf(o.z), f2bf(o.w));
    }
}

// ---------------- pool: attention pooling + cat build + distributed head-weight cast ----------------
__global__ __launch_bounds__(256) void pool_kernel(const int* __restrict__ ctx_ids,
                                                   const int* __restrict__ miss_ids,
                                                   const int* __restrict__ vocab_to_fg,
                                                   const float* __restrict__ emb_table,
                                                   const float* __restrict__ graph,
                                                   const float* __restrict__ attn_w,
                                                   const float* __restrict__ attn_b,
                                                   const float* __restrict__ fusion_w,
                                                   const float* __restrict__ proj1_w,
                                                   const float* __restrict__ proj2_w,
                                                   unsigned short* __restrict__ qinb,
                                                   unsigned short* __restrict__ catb,
                                                   unsigned short* __restrict__ fwb,
                                                   unsigned short* __restrict__ p1b,
                                                   unsigned short* __restrict__ p2b) {
    int b = blockIdx.x;
    int tid = threadIdx.x;
    __shared__ float ctx[CTXL][129];
    __shared__ float aw[128];
    __shared__ float lg[64];

    if (tid < 128) {
        int i = b * 128 + tid;
        if (i < 32768) fwb[i] = f2bf(fusion_w[i]);
        else if (i < 98304) p1b[i - 32768] = f2bf(proj1_w[i - 32768]);
        else p2b[i - 98304] = f2bf(proj2_w[i - 98304]);
    }

    if (tid < 128) aw[tid] = attn_w[tid];
    for (int f = tid; f < CTXL * 32; f += 256) {
        int t = f >> 5, d4 = (f & 31) * 4;
        int vid = ctx_ids[b * CTXL + t];
        float4 v = *(const float4*)(emb_table + (size_t)vid * DIM + d4);
        ctx[t][d4 + 0] = v.x; ctx[t][d4 + 1] = v.y;
        ctx[t][d4 + 2] = v.z; ctx[t][d4 + 3] = v.w;
    }
    __syncthreads();

    if (tid < CTXL) {
        float s = 0.f;
        for (int k = 0; k < 128; k++) s += ctx[tid][k] * aw[k];
        lg[tid] = s + attn_b[0];
    }
    __syncthreads();

    if (tid < 64) {
        float v = (tid < CTXL) ? lg[tid] : -INFINITY;
        float m = v;
        for (int off = 32; off; off >>= 1) m = fmaxf(m, __shfl_xor(m, off));
        float e = (tid < CTXL) ? expf(v - m) : 0.f;
        float s = e;
        for (int off = 32; off; off >>= 1) s += __shfl_xor(s, off);
        if (tid < CTXL) lg[tid] = e / s;
    }
    __syncthreads();

    int mid = miss_ids[b];
    if (tid < 128) {
        float s = 0.f;
        for (int t = 0; t < CTXL; t++) s += lg[t] * ctx[t][tid];
        qinb[(size_t)b * 256 + tid] = f2bf(s);
        catb[(size_t)b * 256 + tid] = f2bf(emb_table[(size_t)mid * DIM + tid]);
    } else {
        int d = tid - 128;
        int fg = vocab_to_fg[mid];
        float gp = (fg >= 0) ? graph[(size_t)fg * DIM + d] : 0.f;
        catb[(size_t)b * 256 + tid] = f2bf(gp);
    }
}

// ---------------- fused head: fusion -> proj1(relu) -> proj2, one block = 16 batch rows ----------------
// WL (128KB) restaged per stage; qin/q1 strips live in LDS (XOR chunk swizzle by row&7).
__global__ __launch_bounds__(256) void head_fused_kernel(const unsigned short* __restrict__ qinb,
                                                         const unsigned short* __restrict__ catb,
                                                         const unsigned short* __restrict__ fwb,
                                                         const unsigned short* __restrict__ p1b,
                                                         const unsigned short* __restrict__ p2b,
                                                         const float* __restrict__ fusion_b,
                                                         const float* __restrict__ proj1_b,
                                                         const float* __restrict__ proj2_b,
                                                         float* __restrict__ query) {
    __shared__ __align__(16) short WL[65536];   // 128 KB
    __shared__ __align__(16) short qs[16][256];  // 8 KB
    __shared__ __align__(16) short q1s[16][256]; // 8 KB
    int tid = threadIdx.x;
    int lane = tid & 63;
    int w = tid >> 6;
    int r16 = lane & 15;
    int kg = lane >> 4;
    int row = blockIdx.x * 16 + r16;

    // qin cols 0..127 (pooled ctx) -> qs swizzled: thread tid = chunk (r = tid>>4, ck = tid&15)
    {
        int r = tid >> 4, ck = tid & 15;
        s16x8 v = *(const s16x8*)(qinb + (size_t)(blockIdx.x * 16 + r) * 256 + ck * 8);
        *(s16x8*)&qs[r][(ck ^ (r & 7)) * 8] = v;
    }
    // stage fusion_w (128x256 bf16 = 64KB): 4096 chunks
    #pragma unroll
    for (int ff = 0; ff < 16; ff++) {
        int f = ff * 256 + tid;
        int c = f >> 5, ck = f & 31;
        s16x8 v = *(const s16x8*)(fwb + (size_t)c * 256 + ck * 8);
        *(s16x8*)&WL[c * 256 + (ck ^ (c & 7)) * 8] = v;
    }
    // A fragments from catb (global)
    s16x8 af[8];
    {
        size_t abase = (size_t)row * 256 + kg * 8;
        #pragma unroll
        for (int ks = 0; ks < 8; ks++) af[ks] = *(const s16x8*)(catb + abase + ks * 32);
    }
    __syncthreads();  // B0: WL(fw) + qs[0:128] ready

    // stage 1: fusion -> qin cols 128..255 (qs)
    #pragma unroll
    for (int ct = 0; ct < 2; ct++) {
        fx4 acc = (fx4){0.f, 0.f, 0.f, 0.f};
        int wrow = w * 32 + ct * 16 + r16;
        #pragma unroll
        for (int ks = 0; ks < 8; ks++) {
            int wch = ((ks * 4 + kg) ^ (r16 & 7)) * 8;
            s16x8 w8 = *(const s16x8*)&WL[wrow * 256 + wch];
            acc = __builtin_amdgcn_mfma_f32_16x16x32_bf16(w8, af[ks], acc, 0, 0, 0);
        }
        int cbase = w * 32 + ct * 16 + kg * 4;
        float x0 = acc[0] + fusion_b[cbase + 0];
        float x1 = acc[1] + fusion_b[cbase + 1];
        float x2 = acc[2] + fusion_b[cbase + 2];
        float x3 = acc[3] + fusion_b[cbase + 3];
        int col = 128 + cbase;
        int c8 = col >> 3, off = col & 7;
        *(ushort4*)&qs[r16][(c8 ^ (r16 & 7)) * 8 + off] =
            make_ushort4(f2bf(x0), f2bf(x1), f2bf(x2), f2bf(x3));
    }
    __syncthreads();  // B1: qs complete, WL free

    // stage proj1_w (256x256 = 128KB): 8192 chunks
    #pragma unroll
    for (int ff = 0; ff < 32; ff++) {
        int f = ff * 256 + tid;
        int c = f >> 5, ck = f & 31;
        s16x8 v = *(const s16x8*)(p1b + (size_t)c * 256 + ck * 8);
        *(s16x8*)&WL[c * 256 + (ck ^ (c & 7)) * 8] = v;
    }
    // A fragments from qs (LDS, swizzled): chunk c8 = kg + ks*4
    #pragma unroll
    for (int ks = 0; ks < 8; ks++) {
        int c8 = kg + ks * 4;
        af[ks] = *(const s16x8*)&qs[r16][(c8 ^ (r16 & 7)) * 8];
    }
    __syncthreads();  // B2: WL(p1) ready

    // stage 2: proj1 + relu -> q1s
    #pragma unroll
    for (int ct = 0; ct < 4; ct++) {
        fx4 acc = (fx4){0.f, 0.f, 0.f, 0.f};
        int wrow = w * 64 + ct * 16 + r16;
        #pragma unroll
        for (int ks = 0; ks < 8; ks++) {
            int wch = ((ks * 4 + kg) ^ (r16 & 7)) * 8;
            s16x8 w8 = *(const s16x8*)&WL[wrow * 256 + wch];
            acc = __builtin_amdgcn_mfma_f32_16x16x32_bf16(w8, af[ks], acc, 0, 0, 0);
        }
        int cbase = w * 64 + ct * 16 + kg * 4;
        float x0 = fmaxf(acc[0] + proj1_b[cbase + 0], 0.f);
        float x1 = fmaxf(acc[1] + proj1_b[cbase + 1], 0.f);
        float x2 = fmaxf(acc[2] + proj1_b[cbase + 2], 0.f);
        float x3 = fmaxf(acc[3] + proj1_b[cbase + 3], 0.f);
        int c8 = cbase >> 3, off = cbase & 7;
        *(ushort4*)&q1s[r16][(c8 ^ (r16 & 7)) * 8 + off] =
            make_ushort4(f2bf(x0), f2bf(x1), f2bf(x2), f2bf(x3));
    }
    __syncthreads();  // B3: q1s complete, WL free

    // stage proj2_w (128x256 = 64KB)
    #pragma unroll
    for (int ff = 0; ff < 16; ff++) {
        int f = ff * 256 + tid;
        int c = f >> 5, ck = f & 31;
        s16x8 v = *(const s16x8*)(p2b + (size_t)c * 256 + ck * 8);
        *(s16x8*)&WL[c * 256 + (ck ^ (c & 7)) * 8] = v;
    }
    #pragma unroll
    for (int ks = 0; ks < 8; ks++) {
        int c8 = kg + ks * 4;
        af[ks] = *(const s16x8*)&q1s[r16][(c8 ^ (r16 & 7)) * 8];
    }
    __syncthreads();  // B4: WL(p2) ready

    // stage 3: proj2 -> query fp32
    #pragma unroll
    for (int ct = 0; ct < 2; ct++) {
        fx4 acc = (fx4){0.f, 0.f, 0.f, 0.f};
        int wrow = w * 32 + ct * 16 + r16;
        #pragma unroll
        for (int ks = 0; ks < 8; ks++) {
            int wch = ((ks * 4 + kg) ^ (r16 & 7)) * 8;
            s16x8 w8 = *(const s16x8*)&WL[wrow * 256 + wch];
            acc = __builtin_amdgcn_mfma_f32_16x16x32_bf16(w8, af[ks], acc, 0, 0, 0);
        }
        int cbase = w * 32 + ct * 16 + kg * 4;
        float4 o;
        o.x = acc[0] + proj2_b[cbase + 0];
        o.y = acc[1] + proj2_b[cbase + 1];
        o.z = acc[2] + proj2_b[cbase + 2];
        o.w = acc[3] + proj2_b[cbase + 3];
        *(float4*)(query + (size_t)row * 128 + cbase) = o;
    }
}

extern "C" void kernel_launch(void* const* d_in, const int* in_sizes, int n_in,
                              void* d_out, int out_size, void* d_ws, size_t ws_size,
                              hipStream_t stream) {
    const int*   edge_index = (const int*)d_in[0];
    const float* norm       = (const float*)d_in[1];
    const int*   ctx_ids    = (const int*)d_in[2];
    const int*   miss_ids   = (const int*)d_in[3];
    const int*   vocab_to_fg= (const int*)d_in[4];
    const float* emb_table  = (const float*)d_in[5];
    const float* fg_emb     = (const float*)d_in[6];
    const float* gc_w       = (const float*)d_in[7];
    const float* bn_gamma   = (const float*)d_in[8];
    const float* bn_beta    = (const float*)d_in[9];
    const float* attn_w     = (const float*)d_in[10];
    const float* attn_b     = (const float*)d_in[11];
    const float* fusion_w   = (const float*)d_in[12];
    const float* fusion_b   = (const float*)d_in[13];
    const float* proj1_w    = (const float*)d_in[14];
    const float* proj1_b    = (const float*)d_in[15];
    const float* proj2_w    = (const float*)d_in[16];
    const float* proj2_b    = (const float*)d_in[17];

    const int* row = edge_index;
    const int* col = edge_index + NE;

    float* ws = (float*)d_ws;
    unsigned short* zb     = (unsigned short*)(ws + OFF_Z);
    unsigned short* Ah     = (unsigned short*)(ws + OFF_AH);
    unsigned short* hbf    = (unsigned short*)(ws + OFF_HBF);
    float*          edge_s = ws + OFF_EDG;
    int*   row_start = (int*)(ws + OFF_RS);
    float* P2        = ws + OFF_P2;
    float* scsh      = ws + OFF_SCSH;
    unsigned short* Wh = (unsigned short*)(ws + OFF_WH);
    unsigned short* Wl = (unsigned short*)(ws + OFF_WL);
    unsigned long long* bkt = (unsigned long long*)(ws + OFF_BKT);
    int*   acnt      = (int*)(ws + OFF_ACNT);
    int*   aofs      = (int*)(ws + OFF_AOFS);
    int*   btot      = (int*)(ws + OFF_BTOT);
    unsigned short* qinb = (unsigned short*)(ws + OFF_QIN);
    unsigned short* catb = (unsigned short*)(ws + OFF_CAT);
    unsigned short* fwb  = (unsigned short*)(ws + OFF_FWB);
    unsigned short* p1b  = (unsigned short*)(ws + OFF_P1B);
    unsigned short* p2b  = (unsigned short*)(ws + OFF_P2B);

    float* query = (float*)d_out;
    float* G     = (float*)d_out + (size_t)NB * DIM;  // graph_embs (final h2)

    // ---- CSR build + prep ----
    csr_prep_kernel<<<6250, 256, 0, stream>>>(row, gc_w, fg_emb, acnt, Wh, Wl, hbf, P2);
    binA_scan<<<NBK, 1024, 0, stream>>>(acnt, aofs, btot);
    binA_scatter<<<NAB, 256, 0, stream>>>(row, col, norm, aofs, bkt);
    binB_kernel<<<NBK, 1024, 0, stream>>>(bkt, btot, row_start, (unsigned long long*)edge_s);

    const int AGG_B = NN / 4;                 // 12500
    const int RES_B = (NN * DIM / 4) / 256;   // 6250

    // ---- layer 1: hbf <- bf16(fg + BN(relu(agg(fg_bf) @ W0^T))) ----
    agg_bf_kernel<<<AGG_B, 256, 0, stream>>>(hbf, row_start, edge_s, Ah);
    gemm_mfma_kernel<<<GEMM_BLOCKS, 256, 0, stream>>>(Ah, Wh, Wl, zb, P2);
    bn_finalize_kernel<<<1, 256, 0, stream>>>(P2, bn_gamma, bn_beta, scsh);
    residual_kernel<<<RES_B, 256, 0, stream>>>(hbf, zb, scsh, nullptr);

    // ---- layer 2: G <- h1 + BN(relu(agg(h1_bf) @ W1^T)) (fp32 final) ----
    agg_bf_kernel<<<AGG_B, 256, 0, stream>>>(hbf, row_start, edge_s, Ah);
    gemm_mfma_kernel<<<GEMM_BLOCKS, 256, 0, stream>>>(Ah, Wh + DIM * DIM, Wl + DIM * DIM, zb, P2);
    bn_finalize_kernel<<<1, 256, 0, stream>>>(P2, bn_gamma + 128, bn_beta + 128, scsh);
    residual_kernel<<<RES_B, 256, 0, stream>>>(hbf, zb, scsh, G);

    // ---- batch head ----
    pool_kernel<<<NB, 256, 0, stream>>>(ctx_ids, miss_ids, vocab_to_fg, emb_table, G,
                                        attn_w, attn_b, fusion_w, proj1_w, proj2_w,
                                        qinb, catb, fwb, p1b, p2b);
    head_fused_kernel<<<64, 256, 0, stream>>>(qinb, catb, fwb, p1b, p2b,
                                              fusion_b, proj1_b, proj2_b, query);
}

// Round 15
// 171.624 us; speedup vs baseline: 1.1317x; 1.1317x over previous
//
#include <hip/hip_runtime.h>

#define NN 50000
#define NE 800000
#define DIM 128
#define NB 1024
#define CTXL 50
#define BN_EPS 1e-5f
#define STRIPS 3125     // NN/16
#define GEMM_BLOCKS 512 // 2 blocks/CU at 64KB LDS
#define NBK 49          // buckets of 1024 rows
#define BCAP 20000      // bucket capacity
#define ABLK 1024       // edges per passA block
#define NAB 782         // ceil(NE/ABLK)

// ---------------- ws layout (float offsets) ----------------
static const size_t OFF_Z    = 0;          // zb bf16 [NN][128]; head aliases here after resid2
static const size_t OFF_AH   = 6400000;    // Ah bf16 [NN][128]; acnt/aofs/btot alias during CSR build
static const size_t OFF_HBF  = 9600000;    // hbf bf16 [NN][128] (fg -> h1)
static const size_t OFF_EDG  = 12800000;   // (col,norm) pairs [NE][2]
static const size_t OFF_RS   = 14400000;   // row_start [NN+1] int
static const size_t OFF_P2   = 14450048;   // BN partials [32][256] f
static const size_t OFF_SCSH = 14550400;   // scale/shift [256] f
static const size_t OFF_WH   = 14550656;   // Wh bf16 [2][128][128]
static const size_t OFF_WL   = 14567040;   // Wl bf16 [2][128][128]
// aliases in dead regions:
static const size_t OFF_BKT  = OFF_Z + 3200000;  // bkt u64 [49][20000] (CSR build only)
static const size_t OFF_ACNT = OFF_AH;           // cnt int [49][784]
static const size_t OFF_AOFS = OFF_AH + 40000;   // ofs int [49][784]
static const size_t OFF_BTOT = OFF_AH + 80000;   // btot int [49]
static const size_t OFF_QIN  = OFF_Z;            // qin bf16 [1024][256] (head phase)
static const size_t OFF_CAT  = OFF_Z + 131072;
static const size_t OFF_FWB  = OFF_Z + 393216;
static const size_t OFF_P1B  = OFF_Z + 409600;
static const size_t OFF_P2B  = OFF_Z + 442368;   // end 458752

typedef __attribute__((ext_vector_type(8))) short s16x8;
typedef __attribute__((ext_vector_type(4))) float fx4;

__device__ __forceinline__ unsigned short f2bf(float f) {
    unsigned u = __float_as_uint(f);
    unsigned r = u + 0x7FFFu + ((u >> 16) & 1u);
    return (unsigned short)(r >> 16);
}
__device__ __forceinline__ float bf2f(unsigned short b) {
    return __uint_as_float((unsigned)b << 16);
}

// ---------------- CSR pass A count + W split + h cast + P2 zero (fused) ----------------
__global__ __launch_bounds__(256) void csr_prep_kernel(const int* __restrict__ row,
                                                       const float* __restrict__ W,
                                                       const float* __restrict__ fg,
                                                       int* __restrict__ cnt,
                                                       unsigned short* __restrict__ Wh,
                                                       unsigned short* __restrict__ Wl,
                                                       unsigned short* __restrict__ hbf,
                                                       float* __restrict__ P2) {
    int i = blockIdx.x * 256 + threadIdx.x;
    if (i < 2 * DIM * DIM) {
        float v = W[i];
        unsigned short h = f2bf(v);
        Wh[i] = h;
        Wl[i] = f2bf(v - bf2f(h));
    }
    if (i < NN * DIM / 4) {
        float4 v = reinterpret_cast<const float4*>(fg)[i];
        reinterpret_cast<ushort4*>(hbf)[i] =
            make_ushort4(f2bf(v.x), f2bf(v.y), f2bf(v.z), f2bf(v.w));
    }
    if (blockIdx.x >= 6218) {  // last 32 blocks zero P2[32][256]
        P2[(blockIdx.x - 6218) * 256 + threadIdx.x] = 0.f;
    }
    if (blockIdx.x < NAB) {
        __shared__ int c[NBK];
        int t = threadIdx.x;
        if (t < NBK) c[t] = 0;
        __syncthreads();
        int base = blockIdx.x * ABLK;
        #pragma unroll
        for (int k = 0; k < 4; k++) {
            int e = base + k * 256 + t;
            if (e < NE) atomicAdd(&c[row[e] >> 10], 1);
        }
        __syncthreads();
        if (t < NBK) cnt[t * 784 + blockIdx.x] = c[t];
    }
}

__global__ __launch_bounds__(1024) void binA_scan(const int* __restrict__ cnt,
                                                  int* __restrict__ ofs,
                                                  int* __restrict__ btot) {
    __shared__ int lds[1024];
    int b = blockIdx.x, t = threadIdx.x;
    int v = (t < NAB) ? cnt[b * 784 + t] : 0;
    lds[t] = v;
    __syncthreads();
    for (int off = 1; off < 1024; off <<= 1) {
        int add = (t >= off) ? lds[t - off] : 0;
        __syncthreads();
        lds[t] += add;
        __syncthreads();
    }
    if (t < NAB) ofs[b * 784 + t] = lds[t] - v;
    if (t == NAB - 1) btot[b] = lds[t];
}

__global__ __launch_bounds__(256) void binA_scatter(const int* __restrict__ row,
                                                    const int* __restrict__ col,
                                                    const float* __restrict__ norm,
                                                    const int* __restrict__ ofs,
                                                    unsigned long long* __restrict__ bkt) {
    __shared__ int c[NBK], bofs[NBK], brsv[NBK];
    __shared__ unsigned long long stage[ABLK];
    __shared__ unsigned char stgb[ABLK];
    int t = threadIdx.x;
    if (t < NBK) c[t] = 0;
    __syncthreads();
    int base = blockIdx.x * ABLK;
    int my_b[4], my_i[4];
    unsigned long long my_pk[4];
    #pragma unroll
    for (int k = 0; k < 4; k++) {
        int e = base + k * 256 + t;
        if (e < NE) {
            int r = row[e];
            int b = r >> 10;
            my_b[k] = b;
            my_i[k] = atomicAdd(&c[b], 1);
            my_pk[k] = ((unsigned long long)__float_as_uint(norm[e]) << 32)
                     | ((unsigned long long)(unsigned)col[e] << 10)
                     | (unsigned)(r & 1023);
        } else my_b[k] = -1;
    }
    __syncthreads();
    if (t == 0) {
        int s = 0;
        for (int b = 0; b < NBK; b++) { bofs[b] = s; s += c[b]; }
    }
    if (t < NBK) brsv[t] = ofs[t * 784 + blockIdx.x];
    __syncthreads();
    #pragma unroll
    for (int k = 0; k < 4; k++) {
        if (my_b[k] >= 0) {
            int j = bofs[my_b[k]] + my_i[k];
            stage[j] = my_pk[k];
            stgb[j] = (unsigned char)my_b[k];
        }
    }
    __syncthreads();
    int tot = min(NE - base, ABLK);
    for (int j = t; j < tot; j += 256) {
        int b = stgb[j];
        int dst = brsv[b] + (j - bofs[b]);
        if (dst < BCAP) bkt[(size_t)b * BCAP + dst] = stage[j];
    }
}

// pass B fused: histogram + prefix -> row_start, then scatter
__global__ __launch_bounds__(1024) void binB_kernel(const unsigned long long* __restrict__ bkt,
                                                    const int* __restrict__ btot,
                                                    int* __restrict__ row_start,
                                                    unsigned long long* __restrict__ edge_out) {
    __shared__ int c[1024];
    __shared__ int rs[1024];
    __shared__ int gofs_s;
    int b = blockIdx.x, t = threadIdx.x;
    c[t] = 0;
    if (t < 64) {
        int v = (t < b) ? btot[t] : 0;
        #pragma unroll
        for (int off = 32; off; off >>= 1) v += __shfl_down(v, off);
        if (t == 0) gofs_s = v;
    }
    __syncthreads();
    int n = btot[b];
    size_t bb = (size_t)b * BCAP;
    for (int i = t; i < n; i += 1024)
        atomicAdd(&c[(int)(bkt[bb + i] & 1023u)], 1);
    __syncthreads();
    int myc = c[t];
    for (int off = 1; off < 1024; off <<= 1) {
        int add = (t >= off) ? c[t - off] : 0;
        __syncthreads();
        c[t] += add;
        __syncthreads();
    }
    int excl = gofs_s + c[t] - myc;
    rs[t] = excl;
    int r = (b << 10) + t;
    if (r <= NN) row_start[r] = excl;
    __syncthreads();
    c[t] = 0;
    __syncthreads();
    for (int i = t; i < n; i += 1024) {
        unsigned long long pk = bkt[bb + i];
        int lr = (int)(pk & 1023u);
        unsigned colv = (unsigned)((pk >> 10) & 0xFFFFu);
        unsigned nrm = (unsigned)(pk >> 32);
        int k = atomicAdd(&c[lr], 1);
        edge_out[rs[lr] + k] = ((unsigned long long)nrm << 32) | colv;
    }
}

// ---------------- aggregation: one wave per row, half-wave split, PREDICATED 8-deep batch ----------------
// Every row issues 8 gathers in flight regardless of degree (clamped idx, zero weight OOB) --
// the r14 version's serial tail dominated because half of Poisson(16) rows have deg<16.
__global__ __launch_bounds__(256) void agg_bf_kernel(const unsigned short* __restrict__ hbf,
                                                     const int* __restrict__ row_start,
                                                     const float* __restrict__ edge_s,
                                                     unsigned short* __restrict__ Ah) {
    int gw = (blockIdx.x * 256 + threadIdx.x) >> 6;
    int lane = threadIdx.x & 63;
    int half = lane >> 5;
    int c4 = (lane & 31) * 4;
    if (gw >= NN) return;
    int s = row_start[gw];
    int e = row_start[gw + 1];
    const int2* ep = (const int2*)edge_s;
    float a0 = 0.f, a1 = 0.f, a2 = 0.f, a3 = 0.f;
    int elast = e - 1;
    for (int j = s + half; j < e; j += 16) {
        int2 p[8];
        ushort4 v[8];
        float wt[8];
        #pragma unroll
        for (int k = 0; k < 8; k++) {
            int idx = j + 2 * k;
            p[k] = ep[min(idx, elast)];
            wt[k] = (idx < e) ? __int_as_float(p[k].y) : 0.f;
        }
        #pragma unroll
        for (int k = 0; k < 8; k++) v[k] = *(const ushort4*)(hbf + (size_t)p[k].x * DIM + c4);
        #pragma unroll
        for (int k = 0; k < 8; k++) {
            a0 = fmaf(wt[k], bf2f(v[k].x), a0); a1 = fmaf(wt[k], bf2f(v[k].y), a1);
            a2 = fmaf(wt[k], bf2f(v[k].z), a2); a3 = fmaf(wt[k], bf2f(v[k].w), a3);
        }
    }
    a0 += __shfl_xor(a0, 32); a1 += __shfl_xor(a1, 32);
    a2 += __shfl_xor(a2, 32); a3 += __shfl_xor(a3, 32);
    if (half == 0) {
        *(ushort4*)(Ah + (size_t)gw * DIM + c4) =
            make_ushort4(f2bf(a0), f2bf(a1), f2bf(a2), f2bf(a3));
    }
}

// ---------------- z = relu(agg @ W^T): full W in 64KB LDS; BN partials -> P2[32][256] atomic ----
__global__ __launch_bounds__(256) void gemm_mfma_kernel(const unsigned short* __restrict__ Ah,
                                                        const unsigned short* __restrict__ Wh,
                                                        const unsigned short* __restrict__ Wl,
                                                        unsigned short* __restrict__ zb,
                                                        float* __restrict__ P2) {
    __shared__ __align__(16) short Wlds[2][128][128];  // 64 KB
    int tid = threadIdx.x;
    int lane = tid & 63;
    int w = tid >> 6;
    int r16 = lane & 15;
    int kg = lane >> 4;

    #pragma unroll
    for (int ff = 0; ff < 16; ff++) {
        int f = ff * 256 + tid;
        int plane = f >> 11;
        int c = (f >> 4) & 127;
        int ck = f & 15;
        const unsigned short* srcp = (plane ? Wl : Wh) + (size_t)c * DIM + ck * 8;
        *(s16x8*)&Wlds[plane][c][(ck ^ (c & 7)) * 8] = *(const s16x8*)srcp;
    }
    __syncthreads();

    float bsum[2][4] = {{0.f}}, bsq[2][4] = {{0.f}};

    for (int strip = blockIdx.x; strip < STRIPS; strip += GEMM_BLOCKS) {
        size_t abase = (size_t)(strip * 16 + r16) * DIM + kg * 8;
        s16x8 b[4];
        #pragma unroll
        for (int ks = 0; ks < 4; ks++) b[ks] = *(const s16x8*)(Ah + abase + ks * 32);

        fx4 acc[2];
        acc[0] = (fx4){0.f, 0.f, 0.f, 0.f};
        acc[1] = (fx4){0.f, 0.f, 0.f, 0.f};
        #pragma unroll
        for (int ks = 0; ks < 4; ks++) {
            #pragma unroll
            for (int ct = 0; ct < 2; ct++) {
                int wrow = w * 32 + ct * 16 + r16;
                int wch = ((ks * 4 + kg) ^ (r16 & 7)) * 8;
                s16x8 wh8 = *(const s16x8*)&Wlds[0][wrow][wch];
                s16x8 wl8 = *(const s16x8*)&Wlds[1][wrow][wch];
                acc[ct] = __builtin_amdgcn_mfma_f32_16x16x32_bf16(wh8, b[ks], acc[ct], 0, 0, 0);
                acc[ct] = __builtin_amdgcn_mfma_f32_16x16x32_bf16(wl8, b[ks], acc[ct], 0, 0, 0);
            }
        }
        size_t zrow = (size_t)(strip * 16 + r16) * DIM + w * 32 + kg * 4;
        #pragma unroll
        for (int ct = 0; ct < 2; ct++) {
            float x0 = fmaxf(acc[ct][0], 0.f);
            float x1 = fmaxf(acc[ct][1], 0.f);
            float x2 = fmaxf(acc[ct][2], 0.f);
            float x3 = fmaxf(acc[ct][3], 0.f);
            bsum[ct][0] += x0; bsq[ct][0] += x0 * x0;
            bsum[ct][1] += x1; bsq[ct][1] += x1 * x1;
            bsum[ct][2] += x2; bsq[ct][2] += x2 * x2;
            bsum[ct][3] += x3; bsq[ct][3] += x3 * x3;
            *(ushort4*)(zb + zrow + ct * 16) = make_ushort4(f2bf(x0), f2bf(x1), f2bf(x2), f2bf(x3));
        }
    }

    int prow = (blockIdx.x & 31) * 256;
    #pragma unroll
    for (int ct = 0; ct < 2; ct++) {
        #pragma unroll
        for (int jj = 0; jj < 4; jj++) {
            float s = bsum[ct][jj], q = bsq[ct][jj];
            #pragma unroll
            for (int off = 1; off <= 8; off <<= 1) {
                s += __shfl_xor(s, off);
                q += __shfl_xor(q, off);
            }
            if (r16 == 0) {
                int ch = w * 32 + ct * 16 + kg * 4 + jj;
                unsafeAtomicAdd(&P2[prow + ch], s);
                unsafeAtomicAdd(&P2[prow + 128 + ch], q);
            }
        }
    }
}

// ---------------- BN finalize: 32-row reduce, self-zero P2 ----------------
__global__ __launch_bounds__(256) void bn_finalize_kernel(float* __restrict__ P2,
                                                          const float* __restrict__ gamma,
                                                          const float* __restrict__ beta,
                                                          float* __restrict__ scsh) {
    __shared__ float tot[256];
    int t = threadIdx.x;
    float s = 0.f;
    #pragma unroll
    for (int r = 0; r < 32; r++) s += P2[r * 256 + t];
    tot[t] = s;
    __syncthreads();
    if (t < 128) {
        float sum = tot[t];
        float sq  = tot[128 + t];
        float mu = sum * (1.f / (float)NN);
        float var = sq * (1.f / (float)NN) - mu * mu;
        float sc = gamma[t] / sqrtf(var + BN_EPS);
        scsh[t] = sc;
        scsh[128 + t] = beta[t] - mu * sc;
    }
    #pragma unroll
    for (int r = 0; r < 32; r++) P2[r * 256 + t] = 0.f;
}

// ---------------- residual: h_new = h_bf + zb*scale + shift; write hbf (layer1) or G fp32 (layer2) ----
__global__ __launch_bounds__(256) void residual_kernel(unsigned short* __restrict__ hbf,
                                                       const unsigned short* __restrict__ zb,
                                                       const float* __restrict__ scsh,
                                                       float* __restrict__ Gout) {
    int i = blockIdx.x * 256 + threadIdx.x;
    if (i >= NN * DIM / 4) return;
    int c = (i * 4) & 127;
    ushort4 z4 = reinterpret_cast<const ushort4*>(zb)[i];
    ushort4 h4 = reinterpret_cast<const ushort4*>(hbf)[i];
    float4 sc = *reinterpret_cast<const float4*>(scsh + c);
    float4 sh = *reinterpret_cast<const float4*>(scsh + 128 + c);
    float4 o;
    o.x = bf2f(h4.x) + bf2f(z4.x) * sc.x + sh.x;
    o.y = bf2f(h4.y) + bf2f(z4.y) * sc.y + sh.y;
    o.z = bf2f(h4.z) + bf2f(z4.z) * sc.z + sh.z;
    o.w = bf2f(h4.w) + bf2f(z4.w) * sc.w + sh.w;
    if (Gout) {
        reinterpret_cast<float4*>(Gout)[i] = o;
    } else {
        reinterpret_cast<ushort4*>(hbf)[i] =
            make_ushort4(f2bf(o.x), f2bf(o.y), f2bf(o.z), f2bf(o.w));
    }
}

// ---------------- pool: attention pooling + cat build + distributed head-weight cast ----------------
__global__ __launch_bounds__(256) void pool_kernel(const int* __restrict__ ctx_ids,
                                                   const int* __restrict__ miss_ids,
                                                   const int* __restrict__ vocab_to_fg,
                                                   const float* __restrict__ emb_table,
                                                   const float* __restrict__ graph,
                                                   const float* __restrict__ attn_w,
                                                   const float* __restrict__ attn_b,
                                                   const float* __restrict__ fusion_w,
                                                   const float* __restrict__ proj1_w,
                                                   const float* __restrict__ proj2_w,
                                                   unsigned short* __restrict__ qinb,
                                                   unsigned short* __restrict__ catb,
                                                   unsigned short* __restrict__ fwb,
                                                   unsigned short* __restrict__ p1b,
                                                   unsigned short* __restrict__ p2b) {
    int b = blockIdx.x;
    int tid = threadIdx.x;
    __shared__ float ctx[CTXL][129];
    __shared__ float aw[128];
    __shared__ float lg[64];

    if (tid < 128) {
        int i = b * 128 + tid;
        if (i < 32768) fwb[i] = f2bf(fusion_w[i]);
        else if (i < 98304) p1b[i - 32768] = f2bf(proj1_w[i - 32768]);
        else p2b[i - 98304] = f2bf(proj2_w[i - 98304]);
    }

    if (tid < 128) aw[tid] = attn_w[tid];
    for (int f = tid; f < CTXL * 32; f += 256) {
        int t = f >> 5, d4 = (f & 31) * 4;
        int vid = ctx_ids[b * CTXL + t];
        float4 v = *(const float4*)(emb_table + (size_t)vid * DIM + d4);
        ctx[t][d4 + 0] = v.x; ctx[t][d4 + 1] = v.y;
        ctx[t][d4 + 2] = v.z; ctx[t][d4 + 3] = v.w;
    }
    __syncthreads();

    if (tid < CTXL) {
        float s = 0.f;
        for (int k = 0; k < 128; k++) s += ctx[tid][k] * aw[k];
        lg[tid] = s + attn_b[0];
    }
    __syncthreads();

    if (tid < 64) {
        float v = (tid < CTXL) ? lg[tid] : -INFINITY;
        float m = v;
        for (int off = 32; off; off >>= 1) m = fmaxf(m, __shfl_xor(m, off));
        float e = (tid < CTXL) ? expf(v - m) : 0.f;
        float s = e;
        for (int off = 32; off; off >>= 1) s += __shfl_xor(s, off);
        if (tid < CTXL) lg[tid] = e / s;
    }
    __syncthreads();

    int mid = miss_ids[b];
    if (tid < 128) {
        float s = 0.f;
        for (int t = 0; t < CTXL; t++) s += lg[t] * ctx[t][tid];
        qinb[(size_t)b * 256 + tid] = f2bf(s);
        catb[(size_t)b * 256 + tid] = f2bf(emb_table[(size_t)mid * DIM + tid]);
    } else {
        int d = tid - 128;
        int fg = vocab_to_fg[mid];
        float gp = (fg >= 0) ? graph[(size_t)fg * DIM + d] : 0.f;
        catb[(size_t)b * 256 + tid] = f2bf(gp);
    }
}

// ---------------- fused head: fusion -> proj1(relu) -> proj2, one block = 16 batch rows ----------------
__global__ __launch_bounds__(256) void head_fused_kernel(const unsigned short* __restrict__ qinb,
                                                         const unsigned short* __restrict__ catb,
                                                         const unsigned short* __restrict__ fwb,
                                                         const unsigned short* __restrict__ p1b,
                                                         const unsigned short* __restrict__ p2b,
                                                         const float* __restrict__ fusion_b,
                                                         const float* __restrict__ proj1_b,
                                                         const float* __restrict__ proj2_b,
                                                         float* __restrict__ query) {
    __shared__ __align__(16) short WL[65536];   // 128 KB
    __shared__ __align__(16) short qs[16][256];  // 8 KB
    __shared__ __align__(16) short q1s[16][256]; // 8 KB
    int tid = threadIdx.x;
    int lane = tid & 63;
    int w = tid >> 6;
    int r16 = lane & 15;
    int kg = lane >> 4;
    int row = blockIdx.x * 16 + r16;

    {
        int r = tid >> 4, ck = tid & 15;
        s16x8 v = *(const s16x8*)(qinb + (size_t)(blockIdx.x * 16 + r) * 256 + ck * 8);
        *(s16x8*)&qs[r][(ck ^ (r & 7)) * 8] = v;
    }
    #pragma unroll
    for (int ff = 0; ff < 16; ff++) {
        int f = ff * 256 + tid;
        int c = f >> 5, ck = f & 31;
        s16x8 v = *(const s16x8*)(fwb + (size_t)c * 256 + ck * 8);
        *(s16x8*)&WL[c * 256 + (ck ^ (c & 7)) * 8] = v;
    }
    s16x8 af[8];
    {
        size_t abase = (size_t)row * 256 + kg * 8;
        #pragma unroll
        for (int ks = 0; ks < 8; ks++) af[ks] = *(const s16x8*)(catb + abase + ks * 32);
    }
    __syncthreads();

    #pragma unroll
    for (int ct = 0; ct < 2; ct++) {
        fx4 acc = (fx4){0.f, 0.f, 0.f, 0.f};
        int wrow = w * 32 + ct * 16 + r16;
        #pragma unroll
        for (int ks = 0; ks < 8; ks++) {
            int wch = ((ks * 4 + kg) ^ (r16 & 7)) * 8;
            s16x8 w8 = *(const s16x8*)&WL[wrow * 256 + wch];
            acc = __builtin_amdgcn_mfma_f32_16x16x32_bf16(w8, af[ks], acc, 0, 0, 0);
        }
        int cbase = w * 32 + ct * 16 + kg * 4;
        float x0 = acc[0] + fusion_b[cbase + 0];
        float x1 = acc[1] + fusion_b[cbase + 1];
        float x2 = acc[2] + fusion_b[cbase + 2];
        float x3 = acc[3] + fusion_b[cbase + 3];
        int col = 128 + cbase;
        int c8 = col >> 3, off = col & 7;
        *(ushort4*)&qs[r16][(c8 ^ (r16 & 7)) * 8 + off] =
            make_ushort4(f2bf(x0), f2bf(x1), f2bf(x2), f2bf(x3));
    }
    __syncthreads();

    #pragma unroll
    for (int ff = 0; ff < 32; ff++) {
        int f = ff * 256 + tid;
        int c = f >> 5, ck = f & 31;
        s16x8 v = *(const s16x8*)(p1b + (size_t)c * 256 + ck * 8);
        *(s16x8*)&WL[c * 256 + (ck ^ (c & 7)) * 8] = v;
    }
    #pragma unroll
    for (int ks = 0; ks < 8; ks++) {
        int c8 = kg + ks * 4;
        af[ks] = *(const s16x8*)&qs[r16][(c8 ^ (r16 & 7)) * 8];
    }
    __syncthreads();

    #pragma unroll
    for (int ct = 0; ct < 4; ct++) {
        fx4 acc = (fx4){0.f, 0.f, 0.f, 0.f};
        int wrow = w * 64 + ct * 16 + r16;
        #pragma unroll
        for (int ks = 0; ks < 8; ks++) {
            int wch = ((ks * 4 + kg) ^ (r16 & 7)) * 8;
            s16x8 w8 = *(const s16x8*)&WL[wrow * 256 + wch];
            acc = __builtin_amdgcn_mfma_f32_16x16x32_bf16(w8, af[ks], acc, 0, 0, 0);
        }
        int cbase = w * 64 + ct * 16 + kg * 4;
        float x0 = fmaxf(acc[0] + proj1_b[cbase + 0], 0.f);
        float x1 = fmaxf(acc[1] + proj1_b[cbase + 1], 0.f);
        float x2 = fmaxf(acc[2] + proj1_b[cbase + 2], 0.f);
        float x3 = fmaxf(acc[3] + proj1_b[cbase + 3], 0.f);
        int c8 = cbase >> 3, off = cbase & 7;
        *(ushort4*)&q1s[r16][(c8 ^ (r16 & 7)) * 8 + off] =
            make_ushort4(f2bf(x0), f2bf(x1), f2bf(x2), f2bf(x3));
    }
    __syncthreads();

    #pragma unroll
    for (int ff = 0; ff < 16; ff++) {
        int f = ff * 256 + tid;
        int c = f >> 5, ck = f & 31;
        s16x8 v = *(const s16x8*)(p2b + (size_t)c * 256 + ck * 8);
        *(s16x8*)&WL[c * 256 + (ck ^ (c & 7)) * 8] = v;
    }
    #pragma unroll
    for (int ks = 0; ks < 8; ks++) {
        int c8 = kg + ks * 4;
        af[ks] = *(const s16x8*)&q1s[r16][(c8 ^ (r16 & 7)) * 8];
    }
    __syncthreads();

    #pragma unroll
    for (int ct = 0; ct < 2; ct++) {
        fx4 acc = (fx4){0.f, 0.f, 0.f, 0.f};
        int wrow = w * 32 + ct * 16 + r16;
        #pragma unroll
        for (int ks = 0; ks < 8; ks++) {
            int wch = ((ks * 4 + kg) ^ (r16 & 7)) * 8;
            s16x8 w8 = *(const s16x8*)&WL[wrow * 256 + wch];
            acc = __builtin_amdgcn_mfma_f32_16x16x32_bf16(w8, af[ks], acc, 0, 0, 0);
        }
        int cbase = w * 32 + ct * 16 + kg * 4;
        float4 o;
        o.x = acc[0] + proj2_b[cbase + 0];
        o.y = acc[1] + proj2_b[cbase + 1];
        o.z = acc[2] + proj2_b[cbase + 2];
        o.w = acc[3] + proj2_b[cbase + 3];
        *(float4*)(query + (size_t)row * 128 + cbase) = o;
    }
}

extern "C" void kernel_launch(void* const* d_in, const int* in_sizes, int n_in,
                              void* d_out, int out_size, void* d_ws, size_t ws_size,
                              hipStream_t stream) {
    const int*   edge_index = (const int*)d_in[0];
    const float* norm       = (const float*)d_in[1];
    const int*   ctx_ids    = (const int*)d_in[2];
    const int*   miss_ids   = (const int*)d_in[3];
    const int*   vocab_to_fg= (const int*)d_in[4];
    const float* emb_table  = (const float*)d_in[5];
    const float* fg_emb     = (const float*)d_in[6];
    const float* gc_w       = (const float*)d_in[7];
    const float* bn_gamma   = (const float*)d_in[8];
    const float* bn_beta    = (const float*)d_in[9];
    const float* attn_w     = (const float*)d_in[10];
    const float* attn_b     = (const float*)d_in[11];
    const float* fusion_w   = (const float*)d_in[12];
    const float* fusion_b   = (const float*)d_in[13];
    const float* proj1_w    = (const float*)d_in[14];
    const float* proj1_b    = (const float*)d_in[15];
    const float* proj2_w    = (const float*)d_in[16];
    const float* proj2_b    = (const float*)d_in[17];

    const int* row = edge_index;
    const int* col = edge_index + NE;

    float* ws = (float*)d_ws;
    unsigned short* zb     = (unsigned short*)(ws + OFF_Z);
    unsigned short* Ah     = (unsigned short*)(ws + OFF_AH);
    unsigned short* hbf    = (unsigned short*)(ws + OFF_HBF);
    float*          edge_s = ws + OFF_EDG;
    int*   row_start = (int*)(ws + OFF_RS);
    float* P2        = ws + OFF_P2;
    float* scsh      = ws + OFF_SCSH;
    unsigned short* Wh = (unsigned short*)(ws + OFF_WH);
    unsigned short* Wl = (unsigned short*)(ws + OFF_WL);
    unsigned long long* bkt = (unsigned long long*)(ws + OFF_BKT);
    int*   acnt      = (int*)(ws + OFF_ACNT);
    int*   aofs      = (int*)(ws + OFF_AOFS);
    int*   btot      = (int*)(ws + OFF_BTOT);
    unsigned short* qinb = (unsigned short*)(ws + OFF_QIN);
    unsigned short* catb = (unsigned short*)(ws + OFF_CAT);
    unsigned short* fwb  = (unsigned short*)(ws + OFF_FWB);
    unsigned short* p1b  = (unsigned short*)(ws + OFF_P1B);
    unsigned short* p2b  = (unsigned short*)(ws + OFF_P2B);

    float* query = (float*)d_out;
    float* G     = (float*)d_out + (size_t)NB * DIM;

    // ---- CSR build + prep ----
    csr_prep_kernel<<<6250, 256, 0, stream>>>(row, gc_w, fg_emb, acnt, Wh, Wl, hbf, P2);
    binA_scan<<<NBK, 1024, 0, stream>>>(acnt, aofs, btot);
    binA_scatter<<<NAB, 256, 0, stream>>>(row, col, norm, aofs, bkt);
    binB_kernel<<<NBK, 1024, 0, stream>>>(bkt, btot, row_start, (unsigned long long*)edge_s);

    const int AGG_B = NN / 4;                 // 12500
    const int RES_B = (NN * DIM / 4) / 256;   // 6250

    // ---- layer 1 ----
    agg_bf_kernel<<<AGG_B, 256, 0, stream>>>(hbf, row_start, edge_s, Ah);
    gemm_mfma_kernel<<<GEMM_BLOCKS, 256, 0, stream>>>(Ah, Wh, Wl, zb, P2);
    bn_finalize_kernel<<<1, 256, 0, stream>>>(P2, bn_gamma, bn_beta, scsh);
    residual_kernel<<<RES_B, 256, 0, stream>>>(hbf, zb, scsh, nullptr);

    // ---- layer 2 ----
    agg_bf_kernel<<<AGG_B, 256, 0, stream>>>(hbf, row_start, edge_s, Ah);
    gemm_mfma_kernel<<<GEMM_BLOCKS, 256, 0, stream>>>(Ah, Wh + DIM * DIM, Wl + DIM * DIM, zb, P2);
    bn_finalize_kernel<<<1, 256, 0, stream>>>(P2, bn_gamma + 128, bn_beta + 128, scsh);
    residual_kernel<<<RES_B, 256, 0, stream>>>(hbf, zb, scsh, G);

    // ---- batch head ----
    pool_kernel<<<NB, 256, 0, stream>>>(ctx_ids, miss_ids, vocab_to_fg, emb_table, G,
                                        attn_w, attn_b, fusion_w, proj1_w, proj2_w,
                                        qinb, catb, fwb, p1b, p2b);
    head_fused_kernel<<<64, 256, 0, stream>>>(qinb, catb, fwb, p1b, p2b,
                                              fusion_b, proj1_b, proj2_b, query);
}

// Round 16
// 169.880 us; speedup vs baseline: 1.1433x; 1.0103x over previous
//
#include <hip/hip_runtime.h>

#define NN 50000
#define NE 800000
#define DIM 128
#define NB 1024
#define VOCAB 30000
#define CTXL 50
#define BN_EPS 1e-5f
#define STRIPS 3125     // NN/16
#define GEMM_BLOCKS 512 // 2 blocks/CU at 64KB LDS
#define NBK 49          // buckets of 1024 rows
#define BCAP 20000      // bucket capacity
#define ABLK 1024       // edges per passA block
#define NAB 782         // ceil(NE/ABLK)

// ---------------- ws layout (float offsets) ----------------
static const size_t OFF_Z    = 0;          // zb bf16 [NN][128]; head aliases here after resid2
static const size_t OFF_AH   = 6400000;    // Ah bf16 [NN][128]; acnt/aofs/btot alias during CSR build
static const size_t OFF_HBF  = 9600000;    // hbf bf16 [NN][128] (fg -> h1)
static const size_t OFF_EDG  = 12800000;   // (col,norm) pairs [NE][2]
static const size_t OFF_RS   = 14400000;   // row_start [NN+1] int
static const size_t OFF_P2   = 14450048;   // BN partials [32][256] f
static const size_t OFF_SCSH = 14550400;   // scale/shift [256] f
static const size_t OFF_WH   = 14550656;   // Wh bf16 [2][128][128]
static const size_t OFF_WL   = 14567040;   // Wl bf16 [2][128][128]
static const size_t OFF_EMBF = 14583424;   // emb_table bf16 [30000][128] = 960000 f (end 15543424)
// aliases in dead regions:
static const size_t OFF_BKT  = OFF_Z + 3200000;  // bkt u64 [49][20000] (CSR build only)
static const size_t OFF_ACNT = OFF_AH;           // cnt int [49][784]
static const size_t OFF_AOFS = OFF_AH + 40000;   // ofs int [49][784]
static const size_t OFF_BTOT = OFF_AH + 80000;   // btot int [49]
static const size_t OFF_QIN  = OFF_Z;            // qin bf16 [1024][256] (head phase)
static const size_t OFF_CAT  = OFF_Z + 131072;
static const size_t OFF_FWB  = OFF_Z + 393216;
static const size_t OFF_P1B  = OFF_Z + 409600;
static const size_t OFF_P2B  = OFF_Z + 442368;   // end 458752

typedef __attribute__((ext_vector_type(8))) short s16x8;
typedef __attribute__((ext_vector_type(4))) float fx4;

__device__ __forceinline__ unsigned short f2bf(float f) {
    unsigned u = __float_as_uint(f);
    unsigned r = u + 0x7FFFu + ((u >> 16) & 1u);
    return (unsigned short)(r >> 16);
}
__device__ __forceinline__ float bf2f(unsigned short b) {
    return __uint_as_float((unsigned)b << 16);
}

// ---------------- CSR pass A count + W split + fg/emb cast + P2 zero (fused) ----------------
__global__ __launch_bounds__(256) void csr_prep_kernel(const int* __restrict__ row,
                                                       const float* __restrict__ W,
                                                       const float* __restrict__ fg,
                                                       const float* __restrict__ emb,
                                                       int* __restrict__ cnt,
                                                       unsigned short* __restrict__ Wh,
                                                       unsigned short* __restrict__ Wl,
                                                       unsigned short* __restrict__ hbf,
                                                       unsigned short* __restrict__ embf,
                                                       float* __restrict__ P2) {
    int i = blockIdx.x * 256 + threadIdx.x;
    if (i < 2 * DIM * DIM) {
        float v = W[i];
        unsigned short h = f2bf(v);
        Wh[i] = h;
        Wl[i] = f2bf(v - bf2f(h));
    }
    if (i < NN * DIM / 4) {
        float4 v = reinterpret_cast<const float4*>(fg)[i];
        reinterpret_cast<ushort4*>(hbf)[i] =
            make_ushort4(f2bf(v.x), f2bf(v.y), f2bf(v.z), f2bf(v.w));
    }
    if (i < VOCAB * DIM / 4) {  // 960000
        float4 v = reinterpret_cast<const float4*>(emb)[i];
        reinterpret_cast<ushort4*>(embf)[i] =
            make_ushort4(f2bf(v.x), f2bf(v.y), f2bf(v.z), f2bf(v.w));
    }
    if (blockIdx.x >= 6218) {  // last 32 blocks zero P2[32][256]
        P2[(blockIdx.x - 6218) * 256 + threadIdx.x] = 0.f;
    }
    if (blockIdx.x < NAB) {
        __shared__ int c[NBK];
        int t = threadIdx.x;
        if (t < NBK) c[t] = 0;
        __syncthreads();
        int base = blockIdx.x * ABLK;
        #pragma unroll
        for (int k = 0; k < 4; k++) {
            int e = base + k * 256 + t;
            if (e < NE) atomicAdd(&c[row[e] >> 10], 1);
        }
        __syncthreads();
        if (t < NBK) cnt[t * 784 + blockIdx.x] = c[t];
    }
}

__global__ __launch_bounds__(1024) void binA_scan(const int* __restrict__ cnt,
                                                  int* __restrict__ ofs,
                                                  int* __restrict__ btot) {
    __shared__ int lds[1024];
    int b = blockIdx.x, t = threadIdx.x;
    int v = (t < NAB) ? cnt[b * 784 + t] : 0;
    lds[t] = v;
    __syncthreads();
    for (int off = 1; off < 1024; off <<= 1) {
        int add = (t >= off) ? lds[t - off] : 0;
        __syncthreads();
        lds[t] += add;
        __syncthreads();
    }
    if (t < NAB) ofs[b * 784 + t] = lds[t] - v;
    if (t == NAB - 1) btot[b] = lds[t];
}

__global__ __launch_bounds__(256) void binA_scatter(const int* __restrict__ row,
                                                    const int* __restrict__ col,
                                                    const float* __restrict__ norm,
                                                    const int* __restrict__ ofs,
                                                    unsigned long long* __restrict__ bkt) {
    __shared__ int c[NBK], bofs[NBK], brsv[NBK];
    __shared__ unsigned long long stage[ABLK];
    __shared__ unsigned char stgb[ABLK];
    int t = threadIdx.x;
    if (t < NBK) c[t] = 0;
    __syncthreads();
    int base = blockIdx.x * ABLK;
    int my_b[4], my_i[4];
    unsigned long long my_pk[4];
    #pragma unroll
    for (int k = 0; k < 4; k++) {
        int e = base + k * 256 + t;
        if (e < NE) {
            int r = row[e];
            int b = r >> 10;
            my_b[k] = b;
            my_i[k] = atomicAdd(&c[b], 1);
            my_pk[k] = ((unsigned long long)__float_as_uint(norm[e]) << 32)
                     | ((unsigned long long)(unsigned)col[e] << 10)
                     | (unsigned)(r & 1023);
        } else my_b[k] = -1;
    }
    __syncthreads();
    if (t == 0) {
        int s = 0;
        for (int b = 0; b < NBK; b++) { bofs[b] = s; s += c[b]; }
    }
    if (t < NBK) brsv[t] = ofs[t * 784 + blockIdx.x];
    __syncthreads();
    #pragma unroll
    for (int k = 0; k < 4; k++) {
        if (my_b[k] >= 0) {
            int j = bofs[my_b[k]] + my_i[k];
            stage[j] = my_pk[k];
            stgb[j] = (unsigned char)my_b[k];
        }
    }
    __syncthreads();
    int tot = min(NE - base, ABLK);
    for (int j = t; j < tot; j += 256) {
        int b = stgb[j];
        int dst = brsv[b] + (j - bofs[b]);
        if (dst < BCAP) bkt[(size_t)b * BCAP + dst] = stage[j];
    }
}

// pass B fused: histogram + prefix -> row_start, then scatter
__global__ __launch_bounds__(1024) void binB_kernel(const unsigned long long* __restrict__ bkt,
                                                    const int* __restrict__ btot,
                                                    int* __restrict__ row_start,
                                                    unsigned long long* __restrict__ edge_out) {
    __shared__ int c[1024];
    __shared__ int rs[1024];
    __shared__ int gofs_s;
    int b = blockIdx.x, t = threadIdx.x;
    c[t] = 0;
    if (t < 64) {
        int v = (t < b) ? btot[t] : 0;
        #pragma unroll
        for (int off = 32; off; off >>= 1) v += __shfl_down(v, off);
        if (t == 0) gofs_s = v;
    }
    __syncthreads();
    int n = btot[b];
    size_t bb = (size_t)b * BCAP;
    for (int i = t; i < n; i += 1024)
        atomicAdd(&c[(int)(bkt[bb + i] & 1023u)], 1);
    __syncthreads();
    int myc = c[t];
    for (int off = 1; off < 1024; off <<= 1) {
        int add = (t >= off) ? c[t - off] : 0;
        __syncthreads();
        c[t] += add;
        __syncthreads();
    }
    int excl = gofs_s + c[t] - myc;
    rs[t] = excl;
    int r = (b << 10) + t;
    if (r <= NN) row_start[r] = excl;
    __syncthreads();
    c[t] = 0;
    __syncthreads();
    for (int i = t; i < n; i += 1024) {
        unsigned long long pk = bkt[bb + i];
        int lr = (int)(pk & 1023u);
        unsigned colv = (unsigned)((pk >> 10) & 0xFFFFu);
        unsigned nrm = (unsigned)(pk >> 32);
        int k = atomicAdd(&c[lr], 1);
        edge_out[rs[lr] + k] = ((unsigned long long)nrm << 32) | colv;
    }
}

// ---------------- aggregation: one wave per row, QUARTER-wave split, ushort8 loads ----------------
// 4 quarters x 16 lanes x 16B = 4 edges per vmem instr, 32 edges in flight per row (predicated).
__global__ __launch_bounds__(256) void agg_bf_kernel(const unsigned short* __restrict__ hbf,
                                                     const int* __restrict__ row_start,
                                                     const float* __restrict__ edge_s,
                                                     unsigned short* __restrict__ Ah) {
    int gw = (blockIdx.x * 256 + threadIdx.x) >> 6;
    int lane = threadIdx.x & 63;
    int q = lane >> 4;          // quarter 0..3
    int c8 = (lane & 15) * 8;   // 8 channels per lane
    if (gw >= NN) return;
    int s = row_start[gw];
    int e = row_start[gw + 1];
    const int2* ep = (const int2*)edge_s;
    float a0 = 0.f, a1 = 0.f, a2 = 0.f, a3 = 0.f;
    float a4 = 0.f, a5 = 0.f, a6 = 0.f, a7 = 0.f;
    int elast = e - 1;
    for (int j = s + q; j < e; j += 32) {
        int2 p[8];
        float wt[8];
        #pragma unroll
        for (int k = 0; k < 8; k++) {
            int idx = j + 4 * k;
            p[k] = ep[min(idx, elast)];
            wt[k] = (idx < e) ? __int_as_float(p[k].y) : 0.f;
        }
        s16x8 v[8];
        #pragma unroll
        for (int k = 0; k < 8; k++) v[k] = *(const s16x8*)(hbf + (size_t)p[k].x * DIM + c8);
        #pragma unroll
        for (int k = 0; k < 8; k++) {
            a0 = fmaf(wt[k], bf2f((unsigned short)v[k][0]), a0);
            a1 = fmaf(wt[k], bf2f((unsigned short)v[k][1]), a1);
            a2 = fmaf(wt[k], bf2f((unsigned short)v[k][2]), a2);
            a3 = fmaf(wt[k], bf2f((unsigned short)v[k][3]), a3);
            a4 = fmaf(wt[k], bf2f((unsigned short)v[k][4]), a4);
            a5 = fmaf(wt[k], bf2f((unsigned short)v[k][5]), a5);
            a6 = fmaf(wt[k], bf2f((unsigned short)v[k][6]), a6);
            a7 = fmaf(wt[k], bf2f((unsigned short)v[k][7]), a7);
        }
    }
    a0 += __shfl_xor(a0, 16); a0 += __shfl_xor(a0, 32);
    a1 += __shfl_xor(a1, 16); a1 += __shfl_xor(a1, 32);
    a2 += __shfl_xor(a2, 16); a2 += __shfl_xor(a2, 32);
    a3 += __shfl_xor(a3, 16); a3 += __shfl_xor(a3, 32);
    a4 += __shfl_xor(a4, 16); a4 += __shfl_xor(a4, 32);
    a5 += __shfl_xor(a5, 16); a5 += __shfl_xor(a5, 32);
    a6 += __shfl_xor(a6, 16); a6 += __shfl_xor(a6, 32);
    a7 += __shfl_xor(a7, 16); a7 += __shfl_xor(a7, 32);
    if (q == 0) {
        s16x8 ov;
        ov[0] = (short)f2bf(a0); ov[1] = (short)f2bf(a1);
        ov[2] = (short)f2bf(a2); ov[3] = (short)f2bf(a3);
        ov[4] = (short)f2bf(a4); ov[5] = (short)f2bf(a5);
        ov[6] = (short)f2bf(a6); ov[7] = (short)f2bf(a7);
        *(s16x8*)(Ah + (size_t)gw * DIM + c8) = ov;
    }
}

// ---------------- z = relu(agg @ W^T): full W in 64KB LDS; BN partials -> P2[32][256] atomic ----
__global__ __launch_bounds__(256) void gemm_mfma_kernel(const unsigned short* __restrict__ Ah,
                                                        const unsigned short* __restrict__ Wh,
                                                        const unsigned short* __restrict__ Wl,
                                                        unsigned short* __restrict__ zb,
                                                        float* __restrict__ P2) {
    __shared__ __align__(16) short Wlds[2][128][128];  // 64 KB
    int tid = threadIdx.x;
    int lane = tid & 63;
    int w = tid >> 6;
    int r16 = lane & 15;
    int kg = lane >> 4;

    #pragma unroll
    for (int ff = 0; ff < 16; ff++) {
        int f = ff * 256 + tid;
        int plane = f >> 11;
        int c = (f >> 4) & 127;
        int ck = f & 15;
        const unsigned short* srcp = (plane ? Wl : Wh) + (size_t)c * DIM + ck * 8;
        *(s16x8*)&Wlds[plane][c][(ck ^ (c & 7)) * 8] = *(const s16x8*)srcp;
    }
    __syncthreads();

    float bsum[2][4] = {{0.f}}, bsq[2][4] = {{0.f}};

    for (int strip = blockIdx.x; strip < STRIPS; strip += GEMM_BLOCKS) {
        size_t abase = (size_t)(strip * 16 + r16) * DIM + kg * 8;
        s16x8 b[4];
        #pragma unroll
        for (int ks = 0; ks < 4; ks++) b[ks] = *(const s16x8*)(Ah + abase + ks * 32);

        fx4 acc[2];
        acc[0] = (fx4){0.f, 0.f, 0.f, 0.f};
        acc[1] = (fx4){0.f, 0.f, 0.f, 0.f};
        #pragma unroll
        for (int ks = 0; ks < 4; ks++) {
            #pragma unroll
            for (int ct = 0; ct < 2; ct++) {
                int wrow = w * 32 + ct * 16 + r16;
                int wch = ((ks * 4 + kg) ^ (r16 & 7)) * 8;
                s16x8 wh8 = *(const s16x8*)&Wlds[0][wrow][wch];
                s16x8 wl8 = *(const s16x8*)&Wlds[1][wrow][wch];
                acc[ct] = __builtin_amdgcn_mfma_f32_16x16x32_bf16(wh8, b[ks], acc[ct], 0, 0, 0);
                acc[ct] = __builtin_amdgcn_mfma_f32_16x16x32_bf16(wl8, b[ks], acc[ct], 0, 0, 0);
            }
        }
        size_t zrow = (size_t)(strip * 16 + r16) * DIM + w * 32 + kg * 4;
        #pragma unroll
        for (int ct = 0; ct < 2; ct++) {
            float x0 = fmaxf(acc[ct][0], 0.f);
            float x1 = fmaxf(acc[ct][1], 0.f);
            float x2 = fmaxf(acc[ct][2], 0.f);
            float x3 = fmaxf(acc[ct][3], 0.f);
            bsum[ct][0] += x0; bsq[ct][0] += x0 * x0;
            bsum[ct][1] += x1; bsq[ct][1] += x1 * x1;
            bsum[ct][2] += x2; bsq[ct][2] += x2 * x2;
            bsum[ct][3] += x3; bsq[ct][3] += x3 * x3;
            *(ushort4*)(zb + zrow + ct * 16) = make_ushort4(f2bf(x0), f2bf(x1), f2bf(x2), f2bf(x3));
        }
    }

    int prow = (blockIdx.x & 31) * 256;
    #pragma unroll
    for (int ct = 0; ct < 2; ct++) {
        #pragma unroll
        for (int jj = 0; jj < 4; jj++) {
            float s = bsum[ct][jj], q = bsq[ct][jj];
            #pragma unroll
            for (int off = 1; off <= 8; off <<= 1) {
                s += __shfl_xor(s, off);
                q += __shfl_xor(q, off);
            }
            if (r16 == 0) {
                int ch = w * 32 + ct * 16 + kg * 4 + jj;
                unsafeAtomicAdd(&P2[prow + ch], s);
                unsafeAtomicAdd(&P2[prow + 128 + ch], q);
            }
        }
    }
}

// ---------------- BN finalize: 32-row reduce, self-zero P2 ----------------
__global__ __launch_bounds__(256) void bn_finalize_kernel(float* __restrict__ P2,
                                                          const float* __restrict__ gamma,
                                                          const float* __restrict__ beta,
                                                          float* __restrict__ scsh) {
    __shared__ float tot[256];
    int t = threadIdx.x;
    float s = 0.f;
    #pragma unroll
    for (int r = 0; r < 32; r++) s += P2[r * 256 + t];
    tot[t] = s;
    __syncthreads();
    if (t < 128) {
        float sum = tot[t];
        float sq  = tot[128 + t];
        float mu = sum * (1.f / (float)NN);
        float var = sq * (1.f / (float)NN) - mu * mu;
        float sc = gamma[t] / sqrtf(var + BN_EPS);
        scsh[t] = sc;
        scsh[128 + t] = beta[t] - mu * sc;
    }
    #pragma unroll
    for (int r = 0; r < 32; r++) P2[r * 256 + t] = 0.f;
}

// ---------------- residual: h_new = h_bf + zb*scale + shift; write hbf (layer1) or G fp32 (layer2) ----
__global__ __launch_bounds__(256) void residual_kernel(unsigned short* __restrict__ hbf,
                                                       const unsigned short* __restrict__ zb,
                                                       const float* __restrict__ scsh,
                                                       float* __restrict__ Gout) {
    int i = blockIdx.x * 256 + threadIdx.x;
    if (i >= NN * DIM / 4) return;
    int c = (i * 4) & 127;
    ushort4 z4 = reinterpret_cast<const ushort4*>(zb)[i];
    ushort4 h4 = reinterpret_cast<const ushort4*>(hbf)[i];
    float4 sc = *reinterpret_cast<const float4*>(scsh + c);
    float4 sh = *reinterpret_cast<const float4*>(scsh + 128 + c);
    float4 o;
    o.x = bf2f(h4.x) + bf2f(z4.x) * sc.x + sh.x;
    o.y = bf2f(h4.y) + bf2f(z4.y) * sc.y + sh.y;
    o.z = bf2f(h4.z) + bf2f(z4.z) * sc.z + sh.z;
    o.w = bf2f(h4.w) + bf2f(z4.w) * sc.w + sh.w;
    if (Gout) {
        reinterpret_cast<float4*>(Gout)[i] = o;
    } else {
        reinterpret_cast<ushort4*>(hbf)[i] =
            make_ushort4(f2bf(o.x), f2bf(o.y), f2bf(o.z), f2bf(o.w));
    }
}

// ---------------- pool: attention pooling (bf16 emb gathers) + cat build + head-weight cast ----------------
__global__ __launch_bounds__(256) void pool_kernel(const int* __restrict__ ctx_ids,
                                                   const int* __restrict__ miss_ids,
                                                   const int* __restrict__ vocab_to_fg,
                                                   const unsigned short* __restrict__ embf,
                                                   const float* __restrict__ graph,
                                                   const float* __restrict__ attn_w,
                                                   const float* __restrict__ attn_b,
                                                   const float* __restrict__ fusion_w,
                                                   const float* __restrict__ proj1_w,
                                                   const float* __restrict__ proj2_w,
                                                   unsigned short* __restrict__ qinb,
                                                   unsigned short* __restrict__ catb,
                                                   unsigned short* __restrict__ fwb,
                                                   unsigned short* __restrict__ p1b,
                                                   unsigned short* __restrict__ p2b) {
    int b = blockIdx.x;
    int tid = threadIdx.x;
    __shared__ float ctx[CTXL][129];
    __shared__ float aw[128];
    __shared__ float lg[64];

    if (tid < 128) {
        int i = b * 128 + tid;
        if (i < 32768) fwb[i] = f2bf(fusion_w[i]);
        else if (i < 98304) p1b[i - 32768] = f2bf(proj1_w[i - 32768]);
        else p2b[i - 98304] = f2bf(proj2_w[i - 98304]);
    }

    if (tid < 128) aw[tid] = attn_w[tid];
    // ctx staging: bf16 16B gathers (50 rows x 16 chunks)
    for (int f = tid; f < CTXL * 16; f += 256) {
        int t = f >> 4, ch = (f & 15) * 8;
        int vid = ctx_ids[b * CTXL + t];
        s16x8 v = *(const s16x8*)(embf + (size_t)vid * DIM + ch);
        #pragma unroll
        for (int i = 0; i < 8; i++) ctx[t][ch + i] = bf2f((unsigned short)v[i]);
    }
    __syncthreads();

    if (tid < CTXL) {
        float s = 0.f;
        for (int k = 0; k < 128; k++) s += ctx[tid][k] * aw[k];
        lg[tid] = s + attn_b[0];
    }
    __syncthreads();

    if (tid < 64) {
        float v = (tid < CTXL) ? lg[tid] : -INFINITY;
        float m = v;
        for (int off = 32; off; off >>= 1) m = fmaxf(m, __shfl_xor(m, off));
        float e = (tid < CTXL) ? expf(v - m) : 0.f;
        float s = e;
        for (int off = 32; off; off >>= 1) s += __shfl_xor(s, off);
        if (tid < CTXL) lg[tid] = e / s;
    }
    __syncthreads();

    int mid = miss_ids[b];
    if (tid < 128) {
        float s = 0.f;
        for (int t = 0; t < CTXL; t++) s += lg[t] * ctx[t][tid];
        qinb[(size_t)b * 256 + tid] = f2bf(s);
        catb[(size_t)b * 256 + tid] = embf[(size_t)mid * DIM + tid];  // already bf16
    } else {
        int d = tid - 128;
        int fg = vocab_to_fg[mid];
        float gp = (fg >= 0) ? graph[(size_t)fg * DIM + d] : 0.f;
        catb[(size_t)b * 256 + tid] = f2bf(gp);
    }
}

// ---------------- fused head: fusion -> proj1(relu) -> proj2, one block = 16 batch rows ----------------
__global__ __launch_bounds__(256) void head_fused_kernel(const unsigned short* __restrict__ qinb,
                                                         const unsigned short* __restrict__ catb,
                                                         const unsigned short* __restrict__ fwb,
                                                         const unsigned short* __restrict__ p1b,
                                                         const unsigned short* __restrict__ p2b,
                                                         const float* __restrict__ fusion_b,
                                                         const float* __restrict__ proj1_b,
                                                         const float* __restrict__ proj2_b,
                                                         float* __restrict__ query) {
    __shared__ __align__(16) short WL[65536];   // 128 KB
    __shared__ __align__(16) short qs[16][256];  // 8 KB
    __shared__ __align__(16) short q1s[16][256]; // 8 KB
    int tid = threadIdx.x;
    int lane = tid & 63;
    int w = tid >> 6;
    int r16 = lane & 15;
    int kg = lane >> 4;
    int row = blockIdx.x * 16 + r16;

    {
        int r = tid >> 4, ck = tid & 15;
        s16x8 v = *(const s16x8*)(qinb + (size_t)(blockIdx.x * 16 + r) * 256 + ck * 8);
        *(s16x8*)&qs[r][(ck ^ (r & 7)) * 8] = v;
    }
    #pragma unroll
    for (int ff = 0; ff < 16; ff++) {
        int f = ff * 256 + tid;
        int c = f >> 5, ck = f & 31;
        s16x8 v = *(const s16x8*)(fwb + (size_t)c * 256 + ck * 8);
        *(s16x8*)&WL[c * 256 + (ck ^ (c & 7)) * 8] = v;
    }
    s16x8 af[8];
    {
        size_t abase = (size_t)row * 256 + kg * 8;
        #pragma unroll
        for (int ks = 0; ks < 8; ks++) af[ks] = *(const s16x8*)(catb + abase + ks * 32);
    }
    __syncthreads();

    #pragma unroll
    for (int ct = 0; ct < 2; ct++) {
        fx4 acc = (fx4){0.f, 0.f, 0.f, 0.f};
        int wrow = w * 32 + ct * 16 + r16;
        #pragma unroll
        for (int ks = 0; ks < 8; ks++) {
            int wch = ((ks * 4 + kg) ^ (r16 & 7)) * 8;
            s16x8 w8 = *(const s16x8*)&WL[wrow * 256 + wch];
            acc = __builtin_amdgcn_mfma_f32_16x16x32_bf16(w8, af[ks], acc, 0, 0, 0);
        }
        int cbase = w * 32 + ct * 16 + kg * 4;
        float x0 = acc[0] + fusion_b[cbase + 0];
        float x1 = acc[1] + fusion_b[cbase + 1];
        float x2 = acc[2] + fusion_b[cbase + 2];
        float x3 = acc[3] + fusion_b[cbase + 3];
        int col = 128 + cbase;
        int c8 = col >> 3, off = col & 7;
        *(ushort4*)&qs[r16][(c8 ^ (r16 & 7)) * 8 + off] =
            make_ushort4(f2bf(x0), f2bf(x1), f2bf(x2), f2bf(x3));
    }
    __syncthreads();

    #pragma unroll
    for (int ff = 0; ff < 32; ff++) {
        int f = ff * 256 + tid;
        int c = f >> 5, ck = f & 31;
        s16x8 v = *(const s16x8*)(p1b + (size_t)c * 256 + ck * 8);
        *(s16x8*)&WL[c * 256 + (ck ^ (c & 7)) * 8] = v;
    }
    #pragma unroll
    for (int ks = 0; ks < 8; ks++) {
        int c8 = kg + ks * 4;
        af[ks] = *(const s16x8*)&qs[r16][(c8 ^ (r16 & 7)) * 8];
    }
    __syncthreads();

    #pragma unroll
    for (int ct = 0; ct < 4; ct++) {
        fx4 acc = (fx4){0.f, 0.f, 0.f, 0.f};
        int wrow = w * 64 + ct * 16 + r16;
        #pragma unroll
        for (int ks = 0; ks < 8; ks++) {
            int wch = ((ks * 4 + kg) ^ (r16 & 7)) * 8;
            s16x8 w8 = *(const s16x8*)&WL[wrow * 256 + wch];
            acc = __builtin_amdgcn_mfma_f32_16x16x32_bf16(w8, af[ks], acc, 0, 0, 0);
        }
        int cbase = w * 64 + ct * 16 + kg * 4;
        float x0 = fmaxf(acc[0] + proj1_b[cbase + 0], 0.f);
        float x1 = fmaxf(acc[1] + proj1_b[cbase + 1], 0.f);
        float x2 = fmaxf(acc[2] + proj1_b[cbase + 2], 0.f);
        float x3 = fmaxf(acc[3] + proj1_b[cbase + 3], 0.f);
        int c8 = cbase >> 3, off = cbase & 7;
        *(ushort4*)&q1s[r16][(c8 ^ (r16 & 7)) * 8 + off] =
            make_ushort4(f2bf(x0), f2bf(x1), f2bf(x2), f2bf(x3));
    }
    __syncthreads();

    #pragma unroll
    for (int ff = 0; ff < 16; ff++) {
        int f = ff * 256 + tid;
        int c = f >> 5, ck = f & 31;
        s16x8 v = *(const s16x8*)(p2b + (size_t)c * 256 + ck * 8);
        *(s16x8*)&WL[c * 256 + (ck ^ (c & 7)) * 8] = v;
    }
    #pragma unroll
    for (int ks = 0; ks < 8; ks++) {
        int c8 = kg + ks * 4;
        af[ks] = *(const s16x8*)&q1s[r16][(c8 ^ (r16 & 7)) * 8];
    }
    __syncthreads();

    #pragma unroll
    for (int ct = 0; ct < 2; ct++) {
        fx4 acc = (fx4){0.f, 0.f, 0.f, 0.f};
        int wrow = w * 32 + ct * 16 + r16;
        #pragma unroll
        for (int ks = 0; ks < 8; ks++) {
            int wch = ((ks * 4 + kg) ^ (r16 & 7)) * 8;
            s16x8 w8 = *(const s16x8*)&WL[wrow * 256 + wch];
            acc = __builtin_amdgcn_mfma_f32_16x16x32_bf16(w8, af[ks], acc, 0, 0, 0);
        }
        int cbase = w * 32 + ct * 16 + kg * 4;
        float4 o;
        o.x = acc[0] + proj2_b[cbase + 0];
        o.y = acc[1] + proj2_b[cbase + 1];
        o.z = acc[2] + proj2_b[cbase + 2];
        o.w = acc[3] + proj2_b[cbase + 3];
        *(float4*)(query + (size_t)row * 128 + cbase) = o;
    }
}

extern "C" void kernel_launch(void* const* d_in, const int* in_sizes, int n_in,
                              void* d_out, int out_size, void* d_ws, size_t ws_size,
                              hipStream_t stream) {
    const int*   edge_index = (const int*)d_in[0];
    const float* norm       = (const float*)d_in[1];
    const int*   ctx_ids    = (const int*)d_in[2];
    const int*   miss_ids   = (const int*)d_in[3];
    const int*   vocab_to_fg= (const int*)d_in[4];
    const float* emb_table  = (const float*)d_in[5];
    const float* fg_emb     = (const float*)d_in[6];
    const float* gc_w       = (const float*)d_in[7];
    const float* bn_gamma   = (const float*)d_in[8];
    const float* bn_beta    = (const float*)d_in[9];
    const float* attn_w     = (const float*)d_in[10];
    const float* attn_b     = (const float*)d_in[11];
    const float* fusion_w   = (const float*)d_in[12];
    const float* fusion_b   = (const float*)d_in[13];
    const float* proj1_w    = (const float*)d_in[14];
    const float* proj1_b    = (const float*)d_in[15];
    const float* proj2_w    = (const float*)d_in[16];
    const float* proj2_b    = (const float*)d_in[17];

    const int* row = edge_index;
    const int* col = edge_index + NE;

    float* ws = (float*)d_ws;
    unsigned short* zb     = (unsigned short*)(ws + OFF_Z);
    unsigned short* Ah     = (unsigned short*)(ws + OFF_AH);
    unsigned short* hbf    = (unsigned short*)(ws + OFF_HBF);
    float*          edge_s = ws + OFF_EDG;
    int*   row_start = (int*)(ws + OFF_RS);
    float* P2        = ws + OFF_P2;
    float* scsh      = ws + OFF_SCSH;
    unsigned short* Wh = (unsigned short*)(ws + OFF_WH);
    unsigned short* Wl = (unsigned short*)(ws + OFF_WL);
    unsigned short* embf = (unsigned short*)(ws + OFF_EMBF);
    unsigned long long* bkt = (unsigned long long*)(ws + OFF_BKT);
    int*   acnt      = (int*)(ws + OFF_ACNT);
    int*   aofs      = (int*)(ws + OFF_AOFS);
    int*   btot      = (int*)(ws + OFF_BTOT);
    unsigned short* qinb = (unsigned short*)(ws + OFF_QIN);
    unsigned short* catb = (unsigned short*)(ws + OFF_CAT);
    unsigned short* fwb  = (unsigned short*)(ws + OFF_FWB);
    unsigned short* p1b  = (unsigned short*)(ws + OFF_P1B);
    unsigned short* p2b  = (unsigned short*)(ws + OFF_P2B);

    float* query = (float*)d_out;
    float* G     = (float*)d_out + (size_t)NB * DIM;

    // ---- CSR build + prep ----
    csr_prep_kernel<<<6250, 256, 0, stream>>>(row, gc_w, fg_emb, emb_table,
                                              acnt, Wh, Wl, hbf, embf, P2);
    binA_scan<<<NBK, 1024, 0, stream>>>(acnt, aofs, btot);
    binA_scatter<<<NAB, 256, 0, stream>>>(row, col, norm, aofs, bkt);
    binB_kernel<<<NBK, 1024, 0, stream>>>(bkt, btot, row_start, (unsigned long long*)edge_s);

    const int AGG_B = NN / 4;                 // 12500
    const int RES_B = (NN * DIM / 4) / 256;   // 6250

    // ---- layer 1 ----
    agg_bf_kernel<<<AGG_B, 256, 0, stream>>>(hbf, row_start, edge_s, Ah);
    gemm_mfma_kernel<<<GEMM_BLOCKS, 256, 0, stream>>>(Ah, Wh, Wl, zb, P2);
    bn_finalize_kernel<<<1, 256, 0, stream>>>(P2, bn_gamma, bn_beta, scsh);
    residual_kernel<<<RES_B, 256, 0, stream>>>(hbf, zb, scsh, nullptr);

    // ---- layer 2 ----
    agg_bf_kernel<<<AGG_B, 256, 0, stream>>>(hbf, row_start, edge_s, Ah);
    gemm_mfma_kernel<<<GEMM_BLOCKS, 256, 0, stream>>>(Ah, Wh + DIM * DIM, Wl + DIM * DIM, zb, P2);
    bn_finalize_kernel<<<1, 256, 0, stream>>>(P2, bn_gamma + 128, bn_beta + 128, scsh);
    residual_kernel<<<RES_B, 256, 0, stream>>>(hbf, zb, scsh, G);

    // ---- batch head ----
    pool_kernel<<<NB, 256, 0, stream>>>(ctx_ids, miss_ids, vocab_to_fg, embf, G,
                                        attn_w, attn_b, fusion_w, proj1_w, proj2_w,
                                        qinb, catb, fwb, p1b, p2b);
    head_fused_kernel<<<64, 256, 0, stream>>>(qinb, catb, fwb, p1b, p2b,
                                              fusion_b, proj1_b, proj2_b, query);
}